// Round 3
// baseline (274.150 us; speedup 1.0000x reference)
//
#include <hip/hip_runtime.h>

// out[l, i] = exp(l * A[i,i]) * B[i] * C[i] + D,  l in [0, L), i in [0, 256)
// L = 262144, n = 256. Output: 67.1M fp32 = 256 MiB -> HBM-write-bound.
// Floor: 268 MB / 6.5 TB/s (measured fill BW) ~= 41 us.
//
// Layout: one wave (64 lanes x float4) writes exactly one 256-elem row
// (fully coalesced 1 KB per wave-store). Block = 256 threads -> 4 rows per
// iteration, unrolled x2. Grid = 2048 blocks x 128 contiguous rows each
// (8 blocks/CU). Non-temporal stores: pure streaming output, no reuse --
// skip L2 retention (256 MiB >> 32 MiB L2).
//
// NOTE: __builtin_nontemporal_store needs a clang vector type, not HIP's
// float4 struct -> use ext_vector_type(4).

#define SSM_N 256
#define SSM_L 262144
#define SSM_GRID 2048
#define SSM_BLOCK 256

typedef float v4f __attribute__((ext_vector_type(4)));

__global__ __launch_bounds__(SSM_BLOCK) void SSMKernel_56770877718744_kernel(
    const float* __restrict__ A,   // (256, 256), only diagonal used
    const float* __restrict__ B,   // (256, 1)
    const float* __restrict__ C,   // (1, 256)
    const float* __restrict__ D,   // (1,)
    float* __restrict__ out)       // (L, 256)
{
    const int t = threadIdx.x;
    const int q = t & 63;          // float4 slot within row: columns 4q..4q+3
    const int c = q << 2;          // column base
    const int r = t >> 6;          // sub-row 0..3 within a 4-row group

    const float LOG2E = 1.4426950408889634f;

    // Per-column constants (loop-invariant; 256 values total, L1/L2-resident).
    const float a0 = A[(size_t)(c + 0) * SSM_N + (c + 0)] * LOG2E;
    const float a1 = A[(size_t)(c + 1) * SSM_N + (c + 1)] * LOG2E;
    const float a2 = A[(size_t)(c + 2) * SSM_N + (c + 2)] * LOG2E;
    const float a3 = A[(size_t)(c + 3) * SSM_N + (c + 3)] * LOG2E;

    const float bc0 = B[c + 0] * C[c + 0];
    const float bc1 = B[c + 1] * C[c + 1];
    const float bc2 = B[c + 2] * C[c + 2];
    const float bc3 = B[c + 3] * C[c + 3];

    const float d = D[0];

    const int rows_per_block = SSM_L / SSM_GRID;   // 128
    const int row_lo = blockIdx.x * rows_per_block;

    v4f* __restrict__ o4 = (v4f*)out;              // 64 v4f per row

    // Per thread: rows row_lo+r, step 4, 32 rows total; unroll x2.
    #pragma unroll 1
    for (int l = row_lo + r; l < row_lo + rows_per_block; l += 8) {
        const float lf0 = (float)l;        // exact: l < 2^24
        const float lf1 = (float)(l + 4);

        v4f v0;
        v0.x = __builtin_amdgcn_exp2f(lf0 * a0) * bc0 + d;
        v0.y = __builtin_amdgcn_exp2f(lf0 * a1) * bc1 + d;
        v0.z = __builtin_amdgcn_exp2f(lf0 * a2) * bc2 + d;
        v0.w = __builtin_amdgcn_exp2f(lf0 * a3) * bc3 + d;

        v4f v1;
        v1.x = __builtin_amdgcn_exp2f(lf1 * a0) * bc0 + d;
        v1.y = __builtin_amdgcn_exp2f(lf1 * a1) * bc1 + d;
        v1.z = __builtin_amdgcn_exp2f(lf1 * a2) * bc2 + d;
        v1.w = __builtin_amdgcn_exp2f(lf1 * a3) * bc3 + d;

        __builtin_nontemporal_store(v0, &o4[(size_t)l * 64 + q]);
        __builtin_nontemporal_store(v1, &o4[(size_t)(l + 4) * 64 + q]);
    }
}

extern "C" void kernel_launch(void* const* d_in, const int* in_sizes, int n_in,
                              void* d_out, int out_size, void* d_ws, size_t ws_size,
                              hipStream_t stream) {
    // Inputs (setup_inputs order): L (int scalar), A (256x256 f32),
    // B (256x1 f32), C (1x256 f32), D (1 f32).
    const float* A = (const float*)d_in[1];
    const float* B = (const float*)d_in[2];
    const float* C = (const float*)d_in[3];
    const float* D = (const float*)d_in[4];
    float* out = (float*)d_out;

    SSMKernel_56770877718744_kernel<<<SSM_GRID, SSM_BLOCK, 0, stream>>>(A, B, C, D, out);
}

// Round 4
// 263.004 us; speedup vs baseline: 1.0424x; 1.0424x over previous
//
#include <hip/hip_runtime.h>

// out[l, i] = exp(l * A[i,i]) * B[i] * C[i] + D,  l in [0, L), i in [0, 256)
// L = 262144, n = 256. Output: 67.1M fp32 = 256 MiB -> HBM-write-bound.
// Floor: 268 MB / ~6.5 TB/s ~= 41 us for the kernel dispatch. The timed
// region also contains the harness re-poison fills (~208 us for 1.25 GiB),
// so composite floor ~= 250 us. R1 (this structure, plain stores) = 262.8 us.
//
// R3 post-mortem: __builtin_nontemporal_store was neutral-to-negative
// (274.1 us) -> reverted to plain float4 stores (L2 write-combining of
// 64-lane 1 KB wave-stores into full HBM bursts works fine).
//
// Layout: one wave (64 lanes x float4) writes exactly one 256-elem row
// (fully coalesced 1 KB per wave-store). Block = 256 threads -> 4 rows per
// iteration, unrolled x2. Grid = 2048 blocks x 128 contiguous rows each
// (8 blocks/CU on 256 CUs).

#define SSM_N 256
#define SSM_L 262144
#define SSM_GRID 2048
#define SSM_BLOCK 256

__global__ __launch_bounds__(SSM_BLOCK) void SSMKernel_56770877718744_kernel(
    const float* __restrict__ A,   // (256, 256), only diagonal used
    const float* __restrict__ B,   // (256, 1)
    const float* __restrict__ C,   // (1, 256)
    const float* __restrict__ D,   // (1,)
    float* __restrict__ out)       // (L, 256)
{
    const int t = threadIdx.x;
    const int q = t & 63;          // float4 slot within row: columns 4q..4q+3
    const int c = q << 2;          // column base
    const int r = t >> 6;          // sub-row 0..3 within a 4-row group

    const float LOG2E = 1.4426950408889634f;

    // Per-column constants (loop-invariant; 256 values total, L1/L2-resident).
    const float a0 = A[(size_t)(c + 0) * SSM_N + (c + 0)] * LOG2E;
    const float a1 = A[(size_t)(c + 1) * SSM_N + (c + 1)] * LOG2E;
    const float a2 = A[(size_t)(c + 2) * SSM_N + (c + 2)] * LOG2E;
    const float a3 = A[(size_t)(c + 3) * SSM_N + (c + 3)] * LOG2E;

    const float bc0 = B[c + 0] * C[c + 0];
    const float bc1 = B[c + 1] * C[c + 1];
    const float bc2 = B[c + 2] * C[c + 2];
    const float bc3 = B[c + 3] * C[c + 3];

    const float d = D[0];

    const int rows_per_block = SSM_L / SSM_GRID;   // 128
    const int row_lo = blockIdx.x * rows_per_block;

    float4* __restrict__ o4 = (float4*)out;        // 64 float4 per row

    // Per thread: rows row_lo+r, step 4, 32 rows total; unroll x2 for
    // store-level MLP.
    #pragma unroll 1
    for (int l = row_lo + r; l < row_lo + rows_per_block; l += 8) {
        const float lf0 = (float)l;        // exact: l < 2^24
        const float lf1 = (float)(l + 4);

        float4 v0;
        v0.x = __builtin_amdgcn_exp2f(lf0 * a0) * bc0 + d;
        v0.y = __builtin_amdgcn_exp2f(lf0 * a1) * bc1 + d;
        v0.z = __builtin_amdgcn_exp2f(lf0 * a2) * bc2 + d;
        v0.w = __builtin_amdgcn_exp2f(lf0 * a3) * bc3 + d;

        float4 v1;
        v1.x = __builtin_amdgcn_exp2f(lf1 * a0) * bc0 + d;
        v1.y = __builtin_amdgcn_exp2f(lf1 * a1) * bc1 + d;
        v1.z = __builtin_amdgcn_exp2f(lf1 * a2) * bc2 + d;
        v1.w = __builtin_amdgcn_exp2f(lf1 * a3) * bc3 + d;

        o4[(size_t)l * 64 + q] = v0;
        o4[(size_t)(l + 4) * 64 + q] = v1;
    }
}

extern "C" void kernel_launch(void* const* d_in, const int* in_sizes, int n_in,
                              void* d_out, int out_size, void* d_ws, size_t ws_size,
                              hipStream_t stream) {
    // Inputs (setup_inputs order): L (int scalar), A (256x256 f32),
    // B (256x1 f32), C (1x256 f32), D (1 f32).
    const float* A = (const float*)d_in[1];
    const float* B = (const float*)d_in[2];
    const float* C = (const float*)d_in[3];
    const float* D = (const float*)d_in[4];
    float* out = (float*)d_out;

    SSMKernel_56770877718744_kernel<<<SSM_GRID, SSM_BLOCK, 0, stream>>>(A, B, C, D, out);
}